// Round 2
// baseline (8532.510 us; speedup 1.0000x reference)
//
#include <hip/hip_runtime.h>
#include <math.h>

#define TID ((int)threadIdx.x)

static constexpr int Tn  = 1024;
static constexpr int Dn  = 128;
static constexpr int BNn = 256;
static constexpr long SL = 16777216;   // half-slot: 256*512*128 floats (64 MB)

// ---------------------------------------------------------------- utilities
__device__ __forceinline__ float wave_sum(float v) {
  v += __shfl_xor(v, 32); v += __shfl_xor(v, 16); v += __shfl_xor(v, 8);
  v += __shfl_xor(v, 4);  v += __shfl_xor(v, 2);  v += __shfl_xor(v, 1);
  return v;
}

// ---------------------------------------------------------------- K1: (B,T,N,D) -> (BN,T,D)
__global__ __launch_bounds__(256) void transpose_k(const float* __restrict__ z, float* __restrict__ zf) {
  long g = (long)blockIdx.x * 256 + TID;           // float4 index in zf
  int bn = (int)(g >> 15); int rem = (int)(g & 32767);
  int t = rem >> 5; int d4 = rem & 31;
  int b = bn >> 5, n = bn & 31;
  float4 v = ((const float4*)z)[(((long)b * Tn + t) * 32 + n) * 32 + d4];
  ((float4*)zf)[g] = v;
}

// ---------------------------------------------------------------- K2a: DFT argmax pass
__global__ __launch_bounds__(256) void dft_pass1(const float* __restrict__ zf,
                                                 unsigned long long* __restrict__ keyb) {
  int bn = blockIdx.x; int f0 = blockIdx.y * 32;
  __shared__ float tab[1024];
  __shared__ float zch[64][128];
  __shared__ float red_m[8][128];
  __shared__ int   red_f[8][128];
  for (int i = TID; i < 1024; i += 256) tab[i] = cosf((float)i * 6.1359231515425649e-3f);
  int dg = TID & 31, fg = TID >> 5;
  int fr[4];
  #pragma unroll
  for (int u = 0; u < 4; ++u) fr[u] = f0 + fg + 8 * u;
  float aR[4][4] = {{0}}, aI[4][4] = {{0}};
  for (int t0 = 0; t0 < 1024; t0 += 64) {
    __syncthreads();
    #pragma unroll
    for (int i = 0; i < 8; ++i) {
      int f4 = TID + 256 * i; int ttl = f4 >> 5; int c4 = (f4 & 31) * 4;
      *(float4*)&zch[ttl][c4] = *(const float4*)(zf + ((long)bn * Tn + t0 + ttl) * Dn + c4);
    }
    __syncthreads();
    #pragma unroll 4
    for (int ttl = 0; ttl < 64; ++ttl) {
      int t = t0 + ttl;
      float c[4], s[4];
      #pragma unroll
      for (int u = 0; u < 4; ++u) {
        int idx = (fr[u] * t) & 1023;
        c[u] = tab[idx]; s[u] = tab[(idx + 768) & 1023];
      }
      float4 zv = *(float4*)&zch[ttl][dg * 4];
      #pragma unroll
      for (int u = 0; u < 4; ++u) {
        aR[u][0] += zv.x * c[u]; aR[u][1] += zv.y * c[u]; aR[u][2] += zv.z * c[u]; aR[u][3] += zv.w * c[u];
        aI[u][0] -= zv.x * s[u]; aI[u][1] -= zv.y * s[u]; aI[u][2] -= zv.z * s[u]; aI[u][3] -= zv.w * s[u];
      }
    }
  }
  #pragma unroll
  for (int v = 0; v < 4; ++v) {
    float bm = -1.f; int bfq = 1024;
    #pragma unroll
    for (int u = 0; u < 4; ++u) {
      int f = fr[u];
      if (f < 513) {
        float m2 = aR[u][v] * aR[u][v] + aI[u][v] * aI[u][v];
        if (m2 > bm) { bm = m2; bfq = f; }
      }
    }
    red_m[fg][dg * 4 + v] = bm; red_f[fg][dg * 4 + v] = bfq;
  }
  __syncthreads();
  if (TID < 128) {
    int d = TID; float bm = -1.f; int bfq = 1024;
    for (int g = 0; g < 8; ++g) {
      float m = red_m[g][d]; int f = red_f[g][d];
      if (m > bm || (m == bm && f < bfq)) { bm = m; bfq = f; }
    }
    if (bm >= 0.f) {
      unsigned long long kk = ((unsigned long long)__float_as_uint(bm) << 32) | (unsigned)(1023 - bfq);
      atomicMax(&keyb[bn * 128 + d], kk);
    }
  }
}

// ---------------------------------------------------------------- K2b: recompute winning bin
__global__ __launch_bounds__(256) void dft_pass2(const float* __restrict__ zf,
                                                 const unsigned long long* __restrict__ keyb,
                                                 float* __restrict__ amp_re, float* __restrict__ amp_im) {
  int bn = blockIdx.x;
  __shared__ float tab[1024];
  __shared__ float sre[128], sim[128];
  for (int i = TID; i < 1024; i += 256) tab[i] = cosf((float)i * 6.1359231515425649e-3f);
  __syncthreads();
  int d = TID & 127, half = TID >> 7;
  int f = 1023 - (int)(keyb[bn * 128 + d] & 1023ULL);
  float re = 0.f, im = 0.f;
  int idx = (f * (half * 512)) & 1023;
  for (int t = half * 512; t < half * 512 + 512; ++t) {
    float c = tab[idx], s = tab[(idx + 768) & 1023];
    float zv = zf[((long)bn * Tn + t) * Dn + d];
    re += zv * c; im -= zv * s;
    idx = (idx + f) & 1023;
  }
  if (half) { sre[d] = re; sim[d] = im; }
  __syncthreads();
  if (!half) {
    re += sre[d]; im += sim[d];
    float mag = sqrtf(re * re + im * im);
    float factor = mag / (mag + 1e-8f);
    float w = (f == 0 || f == 512) ? 1.f : 2.f;
    float sc = w * (1.f / 1024.f) * factor;
    amp_re[bn * 128 + d] = re * sc;
    amp_im[bn * 128 + d] = im * sc;
  }
}

// ---------------------------------------------------------------- K2c: z_rem = zf - z_sea
__global__ __launch_bounds__(256) void zrem_k(const float* __restrict__ zf,
                                              const unsigned long long* __restrict__ keyb,
                                              const float* __restrict__ amp_re, const float* __restrict__ amp_im,
                                              float* __restrict__ z_rem) {
  __shared__ float tab[1024];
  for (int i = TID; i < 1024; i += 256) tab[i] = cosf((float)i * 6.1359231515425649e-3f);
  __syncthreads();
  long g = (long)blockIdx.x * 256 + TID;
  int bn = (int)(g >> 15); int rem = (int)(g & 32767);
  int t = rem >> 5; int d4 = (rem & 31) * 4;
  float4 zv = ((const float4*)zf)[g];
  float se[4];
  #pragma unroll
  for (int j = 0; j < 4; ++j) {
    int d = d4 + j;
    int f = 1023 - (int)(keyb[bn * 128 + d] & 1023ULL);
    int idx = (f * t) & 1023;
    float cc = tab[idx], ss = tab[(idx + 768) & 1023];
    se[j] = amp_re[bn * 128 + d] * cc - amp_im[bn * 128 + d] * ss;
  }
  ((float4*)z_rem)[g] = make_float4(zv.x - se[0], zv.y - se[1], zv.z - se[2], zv.w - se[3]);
}

// ---------------------------------------------------------------- K3a: alpha (trend mix)
__global__ __launch_bounds__(256) void alpha_k(const float* __restrict__ z_rem,
                                               const float* __restrict__ Wq, const float* __restrict__ bq,
                                               float* __restrict__ alpha) {
  int bn = blockIdx.x;
  __shared__ float sm[128];
  __shared__ float lg[3];
  int d = TID & 127, half = TID >> 7;
  float s = 0.f;
  for (int t = half * 512; t < half * 512 + 512; ++t) s += z_rem[((long)bn * Tn + t) * Dn + d];
  if (!half) sm[d] = s;
  __syncthreads();
  if (half) sm[d] += s;
  __syncthreads();
  if (TID < 3) {
    float acc = 0.f;
    for (int dd = 0; dd < 128; ++dd) acc += sm[dd] * Wq[dd * 3 + TID];
    lg[TID] = acc * (1.f / 1024.f) + bq[TID];
  }
  __syncthreads();
  if (TID < 3) {
    float m = fmaxf(lg[0], fmaxf(lg[1], lg[2]));
    float e = expf(lg[TID] - m);
    float ssum = expf(lg[0] - m) + expf(lg[1] - m) + expf(lg[2] - m);
    alpha[bn * 3 + TID] = e / ssum;
  }
}

// ---------------------------------------------------------------- K3b: z_trend (7-tap conv)
__global__ __launch_bounds__(256) void trend_k(const float* __restrict__ z_rem,
                                               const float* __restrict__ alpha, float* __restrict__ z_trend) {
  long g = (long)blockIdx.x * 256 + TID;
  int bn = (int)(g >> 15); int rem = (int)(g & 32767);
  int t = rem >> 5; int c4 = (rem & 31) * 4;
  float a0 = alpha[bn * 3 + 0], a1 = alpha[bn * 3 + 1], a2 = alpha[bn * 3 + 2];
  float w1 = a0 * (1.f / 3.f) + a1 * (1.f / 5.f) + a2 * (1.f / 7.f);
  float w2 = a1 * (1.f / 5.f) + a2 * (1.f / 7.f);
  float w3 = a2 * (1.f / 7.f);
  float wj[7] = {w3, w2, w1, w1, w1, w2, w3};
  float ax = 0.f, ay = 0.f, az = 0.f, aw = 0.f;
  #pragma unroll
  for (int j = -3; j <= 3; ++j) {
    int tt = t + j;
    if (tt < 0 || tt >= Tn) continue;
    float4 v = *(const float4*)(z_rem + ((long)bn * Tn + tt) * Dn + c4);
    float w = wj[j + 3];
    ax += w * v.x; ay += w * v.y; az += w * v.z; aw += w * v.w;
  }
  ((float4*)z_trend)[g] = make_float4(ax, ay, az, aw);
}

// ---------------------------------------------------------------- generic f32 GEMM (N tile = 128)
enum { GM_PLAIN = 0, GM_FLAT = 1, GM_PMEAN = 2 };

template<int MODE>
__device__ __forceinline__ float4 a_load4(const float* __restrict__ A, int r, int k, int K, int Np, int p) {
  if (MODE == GM_PLAIN) {
    return *(const float4*)(A + (long)r * K + k);
  } else if (MODE == GM_FLAT) {
    int bn = r / Np; int np_ = r - bn * Np;
    int t = np_ * p + (k >> 7);
    if (t < Tn) return *(const float4*)(A + ((long)bn * Tn + t) * Dn + (k & 127));
    return make_float4(0.f, 0.f, 0.f, 0.f);
  } else {  // GM_PMEAN (K must be 128)
    int bn = r / Np; int np_ = r - bn * Np;
    int t0 = np_ * p;
    float4 sv = make_float4(0.f, 0.f, 0.f, 0.f);
    for (int j = 0; j < p; ++j) {
      int t = t0 + j;
      if (t < Tn) {
        float4 v = *(const float4*)(A + ((long)bn * Tn + t) * Dn + k);
        sv.x += v.x; sv.y += v.y; sv.z += v.z; sv.w += v.w;
      }
    }
    float inv = 1.f / (float)p;
    sv.x *= inv; sv.y *= inv; sv.z *= inv; sv.w *= inv;
    return sv;
  }
}

#define FMA_ROW(i, av) \
  acc[i][0] += (av) * bv.x; acc[i][1] += (av) * bv.y; acc[i][2] += (av) * bv.z; acc[i][3] += (av) * bv.w;

template<int MODE>
__global__ __launch_bounds__(256) void gemm_k(const float* __restrict__ A, const float* __restrict__ B,
                                              const float* __restrict__ bias, float* __restrict__ C,
                                              int M, int K, int ldb, int ldc, int Np, int p) {
  __shared__ float As[16][68];
  __shared__ float Bs[16][128];
  int r0 = blockIdx.x * 64;
  int colB = blockIdx.y * 128;
  float acc[8][4] = {{0}};
  int am = TID >> 2, ak = (TID & 3) * 4;
  int bk = TID >> 4, bc = (TID & 15) * 8;
  int tc = TID & 31, tr = TID >> 5;
  for (int k0 = 0; k0 < K; k0 += 16) {
    float4 av = a_load4<MODE>(A, r0 + am, k0 + ak, K, Np, p);
    float4 b0 = *(const float4*)(B + (long)(k0 + bk) * ldb + colB + bc);
    float4 b1 = *(const float4*)(B + (long)(k0 + bk) * ldb + colB + bc + 4);
    __syncthreads();
    As[ak + 0][am] = av.x; As[ak + 1][am] = av.y; As[ak + 2][am] = av.z; As[ak + 3][am] = av.w;
    *(float4*)&Bs[bk][bc] = b0; *(float4*)&Bs[bk][bc + 4] = b1;
    __syncthreads();
    #pragma unroll
    for (int kk = 0; kk < 16; ++kk) {
      float4 bv = *(float4*)&Bs[kk][tc * 4];
      float4 a0 = *(float4*)&As[kk][tr * 8];
      float4 a1 = *(float4*)&As[kk][tr * 8 + 4];
      FMA_ROW(0, a0.x) FMA_ROW(1, a0.y) FMA_ROW(2, a0.z) FMA_ROW(3, a0.w)
      FMA_ROW(4, a1.x) FMA_ROW(5, a1.y) FMA_ROW(6, a1.z) FMA_ROW(7, a1.w)
    }
  }
  float4 bb = make_float4(0.f, 0.f, 0.f, 0.f);
  if (bias) bb = *(const float4*)(bias + colB + tc * 4);
  #pragma unroll
  for (int i = 0; i < 8; ++i) {
    long r = r0 + tr * 8 + i;
    float4 o = make_float4(acc[i][0] + bb.x, acc[i][1] + bb.y, acc[i][2] + bb.z, acc[i][3] + bb.w);
    *(float4*)(C + r * (long)ldc + colB + tc * 4) = o;
  }
}

// ---------------------------------------------------------------- router: cat3 GEMM + gating + top3
// z_sea is NOT materialized: z_sea = zf - z_rem computed on the fly.
__global__ __launch_bounds__(256) void router_k(const float* __restrict__ zf, const float* __restrict__ z_rem,
                                                const float* __restrict__ z_trend,
                                                const float* __restrict__ Wf, const float* __restrict__ bf,
                                                const float* __restrict__ nfeat, const float* __restrict__ nlog,
                                                const float* __restrict__ Wr, const float* __restrict__ br,
                                                const float* __restrict__ Wn, const float* __restrict__ bnb,
                                                float* __restrict__ sparse) {
  __shared__ float As[16][68];
  __shared__ float Bs[16][128];
  __shared__ float Cs[64][132];
  __shared__ float wrn[128][8];
  __shared__ float lrow[64][4];
  long r0 = (long)blockIdx.x * 64;
  float acc[8][4] = {{0}};
  int am = TID >> 2, ak = (TID & 3) * 4;
  int bk = TID >> 4, bc = (TID & 15) * 8;
  int tc = TID & 31, tr = TID >> 5;
  for (int k0 = 0; k0 < 384; k0 += 16) {
    int k = k0 + ak;
    long row = (r0 + am) * 128;
    float4 av;
    if (k < 128) {
      av = *(const float4*)(zf + row + k);
    } else if (k < 256) {
      float4 a = *(const float4*)(zf + row + (k - 128));
      float4 b = *(const float4*)(z_rem + row + (k - 128));
      av = make_float4(a.x - b.x, a.y - b.y, a.z - b.z, a.w - b.w);
    } else {
      av = *(const float4*)(z_trend + row + (k - 256));
    }
    float4 b0 = *(const float4*)(Wf + (long)(k0 + bk) * 128 + bc);
    float4 b1 = *(const float4*)(Wf + (long)(k0 + bk) * 128 + bc + 4);
    __syncthreads();
    As[ak + 0][am] = av.x; As[ak + 1][am] = av.y; As[ak + 2][am] = av.z; As[ak + 3][am] = av.w;
    *(float4*)&Bs[bk][bc] = b0; *(float4*)&Bs[bk][bc + 4] = b1;
    __syncthreads();
    #pragma unroll
    for (int kk = 0; kk < 16; ++kk) {
      float4 bv = *(float4*)&Bs[kk][tc * 4];
      float4 a0 = *(float4*)&As[kk][tr * 8];
      float4 a1 = *(float4*)&As[kk][tr * 8 + 4];
      FMA_ROW(0, a0.x) FMA_ROW(1, a0.y) FMA_ROW(2, a0.z) FMA_ROW(3, a0.w)
      FMA_ROW(4, a1.x) FMA_ROW(5, a1.y) FMA_ROW(6, a1.z) FMA_ROW(7, a1.w)
    }
  }
  for (int idx = TID; idx < 128; idx += 256) {
    #pragma unroll
    for (int c = 0; c < 4; ++c) { wrn[idx][c] = Wr[idx * 4 + c]; wrn[idx][4 + c] = Wn[idx * 4 + c]; }
  }
  #pragma unroll
  for (int i = 0; i < 8; ++i) {
    long r = r0 + tr * 8 + i;
    float4 nfv = *(const float4*)(nfeat + r * 128 + tc * 4);
    Cs[tr * 8 + i][tc * 4 + 0] = acc[i][0] + bf[tc * 4 + 0] + 0.1f * nfv.x;
    Cs[tr * 8 + i][tc * 4 + 1] = acc[i][1] + bf[tc * 4 + 1] + 0.1f * nfv.y;
    Cs[tr * 8 + i][tc * 4 + 2] = acc[i][2] + bf[tc * 4 + 2] + 0.1f * nfv.z;
    Cs[tr * 8 + i][tc * 4 + 3] = acc[i][3] + bf[tc * 4 + 3] + 0.1f * nfv.w;
  }
  __syncthreads();
  int rr = TID >> 2, c = TID & 3;
  float la = 0.f, lb2 = 0.f;
  for (int d = 0; d < 128; ++d) {
    float g = Cs[rr][d];
    la += g * wrn[d][c]; lb2 += g * wrn[d][4 + c];
  }
  long r = r0 + rr;
  float x = lb2 + bnb[c];
  float sp = (x > 0.f) ? x + log1pf(expf(-x)) : log1pf(expf(x));
  float lg = la + br[c] + nlog[r * 4 + c] * sp;
  lrow[rr][c] = lg;
  __syncthreads();
  float l0 = lrow[rr][0], l1 = lrow[rr][1], l2 = lrow[rr][2], l3 = lrow[rr][3];
  float mx = fmaxf(fmaxf(l0, l1), fmaxf(l2, l3));
  float e0 = expf(l0 - mx), e1 = expf(l1 - mx), e2 = expf(l2 - mx), e3 = expf(l3 - mx);
  float s = e0 + e1 + e2 + e3;
  float r0v = e0 / s, r1v = e1 / s, r2v = e2 / s, r3v = e3 / s;
  // zero the min of rw; ties -> later index zeroed (matches top_k keeping lower index)
  int zi = 0; float mv = r0v;
  if (r1v <= mv) { mv = r1v; zi = 1; }
  if (r2v <= mv) { mv = r2v; zi = 2; }
  if (r3v <= mv) { mv = r3v; zi = 3; }
  float rwc = (c == 0) ? r0v : (c == 1) ? r1v : (c == 2) ? r2v : r3v;
  sparse[r * 4 + c] = (c == zi) ? 0.f : rwc;
}

// ---------------------------------------------------------------- per-branch combined local-attn weights
__global__ __launch_bounds__(256) void precompute_k(const float* __restrict__ lqkv_w,
                                                    const float* __restrict__ lqkv_b,
                                                    float* __restrict__ Wql, float* __restrict__ bql,
                                                    float* __restrict__ v1, float* __restrict__ c1) {
  int i = blockIdx.x;
  const float* lw0 = lqkv_w + (long)(i * 3 + 0) * 16384;
  const float* lw1 = lqkv_w + (long)(i * 3 + 1) * 16384;
  const float* lb0 = lqkv_b + (i * 3 + 0) * 128;
  const float* lb1 = lqkv_b + (i * 3 + 1) * 128;
  for (int idx = TID; idx < 16384; idx += 256) {
    int dp = idx >> 7, d = idx & 127;
    float s = 0.f;
    for (int e = 0; e < 128; ++e) s += lw0[dp * 128 + e] * lw1[d * 128 + e];
    Wql[(long)i * 16384 + idx] = s;
  }
  for (int d = TID; d < 128; d += 256) {
    float s = 0.f, s2 = 0.f;
    for (int e = 0; e < 128; ++e) { s += lb0[e] * lw1[d * 128 + e]; s2 += lw0[d * 128 + e] * lb1[e]; }
    bql[i * 128 + d] = s;
    v1[i * 128 + d] = s2;
  }
  if (TID == 0) {
    float s = 0.f;
    for (int e = 0; e < 128; ++e) s += lb0[e] * lb1[e];
    c1[i] = s;
  }
}

// ---------------------------------------------------------------- local attention -> pooled patches
__global__ __launch_bounds__(256) void local_attn(const float* __restrict__ zf, const float* __restrict__ w_vec,
                                                  const float* __restrict__ v1, const float* __restrict__ c1,
                                                  float* __restrict__ pooled, int Np, int p, int ibr) {
  int lane = TID & 63, wid = TID >> 6;
  int r = blockIdx.x * 4 + wid;
  int bn = r / Np, np_ = r - bn * Np;
  int d0 = lane, d1 = lane + 64;
  float wv0 = w_vec[(long)r * 128 + d0];
  float wv1 = w_vec[(long)r * 128 + d1];
  float p0[8], p1[8], sj[8];
  #pragma unroll
  for (int j = 0; j < 8; ++j) {
    p0[j] = 0.f; p1[j] = 0.f;
    if (j < p) {
      int t = np_ * p + j;
      if (t < Tn) {
        const float* src = zf + ((long)bn * Tn + t) * Dn;
        p0[j] = src[d0]; p1[j] = src[d1];
      }
    }
    float v = wv0 * p0[j] + wv1 * p1[j];
    sj[j] = wave_sum(v);
  }
  float pm0 = 0.f, pm1 = 0.f;
  #pragma unroll
  for (int j = 0; j < 8; ++j) if (j < p) { pm0 += p0[j]; pm1 += p1[j]; }
  float invp = 1.f / (float)p;
  pm0 *= invp; pm1 *= invp;
  float qb = wave_sum(pm0 * v1[ibr * 128 + d0] + pm1 * v1[ibr * 128 + d1]) + c1[ibr];
  const float scale = 0.08838834764831845f;
  float mx = -1e30f;
  #pragma unroll
  for (int j = 0; j < 8; ++j) if (j < p) { sj[j] = (sj[j] + qb) * scale; mx = fmaxf(mx, sj[j]); }
  float se = 0.f; float ej[8];
  #pragma unroll
  for (int j = 0; j < 8; ++j) { ej[j] = 0.f; if (j < p) { ej[j] = expf(sj[j] - mx); se += ej[j]; } }
  float inv = 1.f / se;
  float o0 = 0.f, o1 = 0.f;
  #pragma unroll
  for (int j = 0; j < 8; ++j) if (j < p) { float w = ej[j] * inv; o0 += w * p0[j]; o1 += w * p1[j]; }
  pooled[(long)r * 128 + d0] = o0;
  pooled[(long)r * 128 + d1] = o1;
}

// ---------------------------------------------------------------- global sigmoid-softmax attention (lo +=)
__global__ __launch_bounds__(256) void gattn_k(const float* __restrict__ gq, const float* __restrict__ gk,
                                               const float* __restrict__ gv, float* __restrict__ lo, int Np) {
  int mt = blockIdx.x, bn = blockIdx.y;
  int m0 = mt * 32;
  __shared__ float Q[32][132], Kt[32][132], Vt[32][132];
  __shared__ float W[32][33];
  __shared__ float denom[32];
  #pragma unroll
  for (int i = 0; i < 4; ++i) {
    int f4 = TID + 256 * i; int mm = f4 >> 5; int c4 = (f4 & 31) * 4;
    int m = m0 + mm;
    float4 v = (m < Np) ? *(const float4*)(gq + ((long)bn * Np + m) * 128 + c4) : make_float4(0.f, 0.f, 0.f, 0.f);
    *(float4*)&Q[mm][c4] = v;
  }
  if (TID < 32) denom[TID] = 0.f;
  float4 ac0 = make_float4(0.f, 0.f, 0.f, 0.f), ac1 = ac0, ac2 = ac0, ac3 = ac0;
  int mmS = TID >> 3, nnb = (TID & 7) * 4;
  int mb = TID >> 5, e4 = (TID & 31) * 4;
  const float scale = 0.08838834764831845f;
  for (int n0 = 0; n0 < Np; n0 += 32) {
    __syncthreads();
    #pragma unroll
    for (int i = 0; i < 4; ++i) {
      int f4 = TID + 256 * i; int nn = f4 >> 5; int c4 = (f4 & 31) * 4;
      int n = n0 + nn;
      float4 kv = (n < Np) ? *(const float4*)(gk + ((long)bn * Np + n) * 128 + c4) : make_float4(0.f, 0.f, 0.f, 0.f);
      float4 vv = (n < Np) ? *(const float4*)(gv + ((long)bn * Np + n) * 128 + c4) : make_float4(0.f, 0.f, 0.f, 0.f);
      *(float4*)&Kt[nn][c4] = kv;
      *(float4*)&Vt[nn][c4] = vv;
    }
    __syncthreads();
    float s0 = 0.f, s1 = 0.f, s2 = 0.f, s3 = 0.f;
    #pragma unroll 8
    for (int e = 0; e < 128; e += 4) {
      float4 q4 = *(float4*)&Q[mmS][e];
      float4 k0 = *(float4*)&Kt[nnb + 0][e];
      float4 k1 = *(float4*)&Kt[nnb + 1][e];
      float4 k2 = *(float4*)&Kt[nnb + 2][e];
      float4 k3 = *(float4*)&Kt[nnb + 3][e];
      s0 += q4.x * k0.x + q4.y * k0.y + q4.z * k0.z + q4.w * k0.w;
      s1 += q4.x * k1.x + q4.y * k1.y + q4.z * k1.z + q4.w * k1.w;
      s2 += q4.x * k2.x + q4.y * k2.y + q4.z * k2.z + q4.w * k2.w;
      s3 += q4.x * k3.x + q4.y * k3.y + q4.z * k3.z + q4.w * k3.w;
    }
    float sv[4] = {s0, s1, s2, s3};
    #pragma unroll
    for (int u = 0; u < 4; ++u) {
      int n = n0 + nnb + u;
      float w = 0.f;
      if (n < Np) {
        float sg = 1.f / (1.f + expf(-sv[u]));
        w = expf(sg * scale);
      }
      W[mmS][nnb + u] = w;
    }
    __syncthreads();
    if (TID < 32) {
      float dsum = 0.f;
      for (int nn = 0; nn < 32; ++nn) dsum += W[TID][nn];
      denom[TID] += dsum;
    }
    #pragma unroll 4
    for (int nn = 0; nn < 32; ++nn) {
      float4 v4 = *(float4*)&Vt[nn][e4];
      float w0 = W[mb][nn], w1 = W[mb + 8][nn], w2 = W[mb + 16][nn], w3 = W[mb + 24][nn];
      ac0.x += w0 * v4.x; ac0.y += w0 * v4.y; ac0.z += w0 * v4.z; ac0.w += w0 * v4.w;
      ac1.x += w1 * v4.x; ac1.y += w1 * v4.y; ac1.z += w1 * v4.z; ac1.w += w1 * v4.w;
      ac2.x += w2 * v4.x; ac2.y += w2 * v4.y; ac2.z += w2 * v4.z; ac2.w += w2 * v4.w;
      ac3.x += w3 * v4.x; ac3.y += w3 * v4.y; ac3.z += w3 * v4.z; ac3.w += w3 * v4.w;
    }
  }
  __syncthreads();
  #pragma unroll
  for (int kk2 = 0; kk2 < 4; ++kk2) {
    int m = m0 + mb + 8 * kk2;
    if (m < Np) {
      float inv = 1.f / denom[mb + 8 * kk2];
      float* lp = lo + ((long)bn * Np + m) * 128 + e4;
      float4 cur = *(float4*)lp;
      float4 a = (kk2 == 0) ? ac0 : (kk2 == 1) ? ac1 : (kk2 == 2) ? ac2 : ac3;
      cur.x += a.x * inv; cur.y += a.y * inv; cur.z += a.z * inv; cur.w += a.w * inv;
      *(float4*)lp = cur;
    }
  }
}

// ---------------------------------------------------------------- convT scatter + gate, DIRECT to out
// out_final[b, o*8 + t/128, n, t&127] += sparse[bn,t,i] * (up[bn,np,o,j] + cb[o])
__global__ __launch_bounds__(256) void scatter2_k(const float* __restrict__ up_t, const float* __restrict__ sparse,
                                                  const float* __restrict__ cb, float* __restrict__ out,
                                                  int Np, int p, int ibr) {
  int bn = blockIdx.x; int t0 = blockIdx.y * 128; int o0 = blockIdx.z * 16;
  __shared__ float tile[16][132];
  int np0 = t0 / p;
  int np1 = (t0 + 127) / p;
  if (np1 > Np - 1) np1 = Np - 1;
  int per = 16 * p;                    // contiguous floats per np_ in the o-tile
  int npi = 256 / per;                 // np_'s handled per iteration
  int sub = TID / per;
  int e   = TID - sub * per;
  int ol = e / p, j = e - ol * p;
  for (int npb = np0; npb <= np1; npb += npi) {
    int np_ = npb + sub;
    if (sub < npi && np_ <= np1) {
      int t = np_ * p + j;
      if (t >= t0 && t < t0 + 128 && t < Tn) {
        tile[ol][t - t0] = up_t[(((long)bn * Np + np_) * 128 + o0 + ol) * (long)p + j];
      }
    }
  }
  __syncthreads();
  int dd = TID & 127, ow = TID >> 7;
  int t = t0 + dd;
  float sp = sparse[((long)bn * 1024 + t) * 4 + ibr];
  int b = bn >> 5, n = bn & 31;
  int thi = t0 >> 7;
  for (int ol2 = ow; ol2 < 16; ol2 += 2) {
    int o = o0 + ol2;
    float v = sp * (tile[ol2][dd] + cb[o]);
    long idx = (((long)b * 1024 + o * 8 + thi) * 32 + n) * 128 + dd;
    out[idx] += v;
  }
}

// ---------------------------------------------------------------- launch
extern "C" void kernel_launch(void* const* d_in, const int* in_sizes, int n_in,
                              void* d_out, int out_size, void* d_ws, size_t ws_size,
                              hipStream_t stream) {
  const float* z      = (const float*)d_in[0];
  const float* nfeat  = (const float*)d_in[1];
  const float* nlog   = (const float*)d_in[2];
  const float* Wq_tr  = (const float*)d_in[3];
  const float* bq_tr  = (const float*)d_in[4];
  const float* Wf     = (const float*)d_in[5];
  const float* bf     = (const float*)d_in[6];
  const float* Wr     = (const float*)d_in[7];
  const float* br     = (const float*)d_in[8];
  const float* Wn     = (const float*)d_in[9];
  const float* bnb    = (const float*)d_in[10];
  const float* lqkv_w = (const float*)d_in[11];
  const float* lqkv_b = (const float*)d_in[12];
  const float* gqkvb  = (const float*)d_in[13];
  const float* proj_w = (const float*)d_in[14];
  const float* proj_b = (const float*)d_in[15];
  const float* conv_b = (const float*)d_in[16];
  const float* gqkv_w[4] = {(const float*)d_in[17], (const float*)d_in[19],
                            (const float*)d_in[21], (const float*)d_in[23]};
  const float* conv_w[4] = {(const float*)d_in[18], (const float*)d_in[20],
                            (const float*)d_in[22], (const float*)d_in[24]};
  float* out = (float*)d_out;
  float* ws = (float*)d_ws;

  // ---- workspace layout (floats); total = 101,910,592 floats = 407.6 MB
  float* zf     = ws;                         // 33,554,432  (persistent)
  float* LOOP   = ws + 2 * SL;                // 67,108,864  (phase-aliased)
  float* sparse = ws + 6 * SL;                // 1,048,576
  unsigned long long* keyb = (unsigned long long*)(sparse + 1048576);  // 65,536 floats worth
  float* amp_re = sparse + 1048576 + 65536;   // 32,768
  float* amp_im = amp_re + 32768;             // 32,768
  float* alpha  = amp_im + 32768;             // 1,024
  float* Wql    = alpha + 1024;               // 65,536
  float* bql    = Wql + 65536;                // 512
  float* v1     = bql + 512;                  // 512
  float* c1     = v1 + 512;                   // 64

  // pre-phase aliases inside LOOP
  float* z_rem   = LOOP;                      // 2 SL
  float* z_trend = LOOP + 2 * SL;             // 2 SL

  hipMemsetAsync(out, 0, (size_t)out_size * sizeof(float), stream);
  hipMemsetAsync(keyb, 0, (size_t)32768 * sizeof(unsigned long long), stream);

  transpose_k<<<32768, 256, 0, stream>>>(z, zf);
  dft_pass1<<<dim3(256, 17), 256, 0, stream>>>(zf, keyb);
  dft_pass2<<<256, 256, 0, stream>>>(zf, keyb, amp_re, amp_im);
  zrem_k<<<32768, 256, 0, stream>>>(zf, keyb, amp_re, amp_im, z_rem);
  alpha_k<<<256, 256, 0, stream>>>(z_rem, Wq_tr, bq_tr, alpha);
  trend_k<<<32768, 256, 0, stream>>>(z_rem, alpha, z_trend);
  router_k<<<4096, 256, 0, stream>>>(zf, z_rem, z_trend, Wf, bf, nfeat, nlog, Wr, br, Wn, bnb, sparse);
  precompute_k<<<4, 256, 0, stream>>>(lqkv_w, lqkv_b, Wql, bql, v1, c1);

  const int PS[4]  = {2, 4, 6, 8};
  const int NPs[4] = {512, 256, 171, 128};
  for (int i = 0; i < 4; ++i) {
    int p = PS[i], Np = NPs[i];
    int M = BNn * Np;
    // slot plan inside LOOP (4 half-slots): w_vec->s0, pooled->s1, lob->s2,
    // gq->s0, gk->s1, gv->s3, fused->s0, up_t->s1.. (spans <= s1+2.01 half-slots)
    float* w_vec  = LOOP + 0 * SL;
    float* pooled = LOOP + 1 * SL;
    float* lob    = LOOP + 2 * SL;
    float* gqb    = LOOP + 0 * SL;
    float* gkb    = LOOP + 1 * SL;
    float* gvb    = LOOP + 3 * SL;
    float* fusedb = LOOP + 0 * SL;
    float* up_t   = LOOP + 1 * SL;
    long gsz = (long)p * 128 * 128;

    gemm_k<GM_PMEAN><<<dim3(M / 64, 1), 256, 0, stream>>>(zf, Wql + (long)i * 16384, bql + i * 128,
                                                          w_vec, M, 128, 128, 128, Np, p);
    local_attn<<<M / 4, 256, 0, stream>>>(zf, w_vec, v1, c1, pooled, Np, p, i);
    gemm_k<GM_PLAIN><<<dim3(M / 64, 1), 256, 0, stream>>>(pooled, lqkv_w + (long)(i * 3 + 2) * 16384,
                                                          lqkv_b + (i * 3 + 2) * 128, lob, M, 128, 128, 128, Np, p);
    gemm_k<GM_FLAT><<<dim3(M / 64, 1), 256, 0, stream>>>(zf, gqkv_w[i] + 0 * gsz, gqkvb + (i * 3 + 0) * 128,
                                                         gqb, M, p * 128, 128, 128, Np, p);
    gemm_k<GM_FLAT><<<dim3(M / 64, 1), 256, 0, stream>>>(zf, gqkv_w[i] + 1 * gsz, gqkvb + (i * 3 + 1) * 128,
                                                         gkb, M, p * 128, 128, 128, Np, p);
    gemm_k<GM_FLAT><<<dim3(M / 64, 1), 256, 0, stream>>>(zf, gqkv_w[i] + 2 * gsz, gqkvb + (i * 3 + 2) * 128,
                                                         gvb, M, p * 128, 128, 128, Np, p);
    gattn_k<<<dim3((Np + 31) / 32, 256), 256, 0, stream>>>(gqb, gkb, gvb, lob, Np);
    gemm_k<GM_PLAIN><<<dim3(M / 64, 1), 256, 0, stream>>>(lob, proj_w + (long)i * 16384, proj_b + i * 128,
                                                          fusedb, M, 128, 128, 128, Np, p);
    gemm_k<GM_PLAIN><<<dim3(M / 64, p), 256, 0, stream>>>(fusedb, conv_w[i], nullptr, up_t,
                                                          M, 128, 128 * p, 128 * p, Np, p);
    scatter2_k<<<dim3(256, 8, 8), 256, 0, stream>>>(up_t, sparse, conv_b + i * 128, out, Np, p, i);
  }
}